// Round 1
// baseline (824.617 us; speedup 1.0000x reference)
//
#include <hip/hip_runtime.h>
#include <math.h>

#define B_  4
#define T_  2048
#define C_  1024
#define NH_ 16
#define HS_ 64
#define M_  (B_ * T_)          // 8192
#define BH_ (B_ * NH_)         // 64

typedef __bf16 bf16_t;
typedef __bf16 bf16x8 __attribute__((ext_vector_type(8)));
typedef float  f32x4  __attribute__((ext_vector_type(4)));

__device__ __forceinline__ f32x4 mfma16(bf16x8 a, bf16x8 b, f32x4 c) {
    return __builtin_amdgcn_mfma_f32_16x16x32_bf16(a, b, c, 0, 0, 0);
}

// ---------------- prep kernels ----------------

// x (fp32) -> bf16, 8 elements per thread
__global__ void cvt_x(const float* __restrict__ x, bf16_t* __restrict__ xb) {
    int i = blockIdx.x * blockDim.x + threadIdx.x;          // 1,048,576 threads
    const float4* src = reinterpret_cast<const float4*>(x);
    float4 u = src[2 * i], v = src[2 * i + 1];
    bf16x8 o;
    o[0] = (bf16_t)u.x; o[1] = (bf16_t)u.y; o[2] = (bf16_t)u.z; o[3] = (bf16_t)u.w;
    o[4] = (bf16_t)v.x; o[5] = (bf16_t)v.y; o[6] = (bf16_t)v.z; o[7] = (bf16_t)v.w;
    *reinterpret_cast<bf16x8*>(xb + (size_t)i * 8) = o;
}

// W[K=1024][N=1024] fp32 -> Wt[N][K] bf16 (tiled transpose via LDS)
__global__ void wtrans(const float* __restrict__ W, bf16_t* __restrict__ Wt) {
    __shared__ float tile[32][33];
    int bx = blockIdx.x, by = blockIdx.y;
    int tx = threadIdx.x, ty = threadIdx.y;
    #pragma unroll
    for (int j = 0; j < 4; ++j)
        tile[ty + j * 8][tx] = W[(size_t)(by * 32 + ty + j * 8) * 1024 + bx * 32 + tx];
    __syncthreads();
    #pragma unroll
    for (int j = 0; j < 4; ++j)
        Wt[(size_t)(bx * 32 + ty + j * 8) * 1024 + by * 32 + tx] = (bf16_t)tile[tx][ty + j * 8];
}

// cos/sin tables [T][32]
__global__ void rope_tab(float* __restrict__ cs, float* __restrict__ sn) {
    int idx = blockIdx.x * blockDim.x + threadIdx.x;        // 65536 threads
    int t = idx >> 5, j = idx & 31;
    float inv = 1.0f / powf(10000.0f, ((float)(2 * j)) / 64.0f);
    float ang = (float)t * inv;
    cs[idx] = cosf(ang);
    sn[idx] = sinf(ang);
}

// ---------------- QKV GEMM ----------------
// A [8192][1024] bf16, Bt [3072][1024] bf16. Epilogue scatters to
// q,k: [BH][T][64], vt: [BH][64][T] (transposed). Biases fp32.
__global__ __launch_bounds__(256) void gemm_qkv(
    const bf16_t* __restrict__ A, const bf16_t* __restrict__ Bt,
    const float* __restrict__ bq, const float* __restrict__ bk, const float* __restrict__ bv,
    bf16_t* __restrict__ outq, bf16_t* __restrict__ outk, bf16_t* __restrict__ outvt) {
    int lane = threadIdx.x & 63;
    int w = threadIdx.x >> 6;
    int rr = lane & 15, g = lane >> 4;
    int mbase = blockIdx.y * 128 + (w >> 1) * 64;
    int nbase = blockIdx.x * 128 + (w & 1) * 64;
    f32x4 acc[4][4] = {};
    const bf16_t* Ap = A + (size_t)(mbase + rr) * 1024 + g * 8;
    const bf16_t* Bp = Bt + (size_t)(nbase + rr) * 1024 + g * 8;
    for (int kk = 0; kk < 1024; kk += 32) {
        bf16x8 a[4], b[4];
        #pragma unroll
        for (int i = 0; i < 4; ++i) {
            a[i] = *reinterpret_cast<const bf16x8*>(Ap + i * 16 * 1024 + kk);
            b[i] = *reinterpret_cast<const bf16x8*>(Bp + i * 16 * 1024 + kk);
        }
        #pragma unroll
        for (int mi = 0; mi < 4; ++mi)
            #pragma unroll
            for (int ni = 0; ni < 4; ++ni)
                acc[mi][ni] = mfma16(a[mi], b[ni], acc[mi][ni]);
    }
    #pragma unroll
    for (int ni = 0; ni < 4; ++ni) {
        int n = nbase + ni * 16 + rr;
        int sel = n >> 10, nn = n & 1023, h = nn >> 6, d = nn & 63;
        float bias = (sel == 0) ? bq[nn] : (sel == 1) ? bk[nn] : bv[nn];
        #pragma unroll
        for (int mi = 0; mi < 4; ++mi) {
            #pragma unroll
            for (int j = 0; j < 4; ++j) {
                int mrow = mbase + mi * 16 + g * 4 + j;
                int bI = mrow >> 11, t = mrow & 2047;
                float val = acc[mi][ni][j] + bias;
                size_t bh = (size_t)(bI * 16 + h);
                if (sel == 0)      outq[(bh * 2048 + t) * 64 + d] = (bf16_t)val;
                else if (sel == 1) outk[(bh * 2048 + t) * 64 + d] = (bf16_t)val;
                else               outvt[(bh * 64 + d) * 2048 + t] = (bf16_t)val;
            }
        }
    }
}

// ---------------- RoPE on q,k (bf16 in-place) ----------------
__global__ void rope_qk(bf16_t* __restrict__ q, bf16_t* __restrict__ k,
                        const float* __restrict__ cs, const float* __restrict__ sn) {
    int idx = blockIdx.x * blockDim.x + threadIdx.x;        // BH*T*8 = 1,048,576
    int seg = idx & 7;
    int t = (idx >> 3) & 2047;
    int bh = idx >> 14;
    float4 cc = *reinterpret_cast<const float4*>(cs + (t << 5) + seg * 4);
    float4 ss = *reinterpret_cast<const float4*>(sn + (t << 5) + seg * 4);
    size_t base = (((size_t)bh << 11) + t) * 64 + seg * 8;
    {
        bf16x8 v = *reinterpret_cast<bf16x8*>(q + base);
        bf16x8 o;
        o[0] = (bf16_t)((float)v[0] * cc.x - (float)v[1] * ss.x);
        o[1] = (bf16_t)((float)v[0] * ss.x + (float)v[1] * cc.x);
        o[2] = (bf16_t)((float)v[2] * cc.y - (float)v[3] * ss.y);
        o[3] = (bf16_t)((float)v[2] * ss.y + (float)v[3] * cc.y);
        o[4] = (bf16_t)((float)v[4] * cc.z - (float)v[5] * ss.z);
        o[5] = (bf16_t)((float)v[4] * ss.z + (float)v[5] * cc.z);
        o[6] = (bf16_t)((float)v[6] * cc.w - (float)v[7] * ss.w);
        o[7] = (bf16_t)((float)v[6] * ss.w + (float)v[7] * cc.w);
        *reinterpret_cast<bf16x8*>(q + base) = o;
    }
    {
        bf16x8 v = *reinterpret_cast<bf16x8*>(k + base);
        bf16x8 o;
        o[0] = (bf16_t)((float)v[0] * cc.x - (float)v[1] * ss.x);
        o[1] = (bf16_t)((float)v[0] * ss.x + (float)v[1] * cc.x);
        o[2] = (bf16_t)((float)v[2] * cc.y - (float)v[3] * ss.y);
        o[3] = (bf16_t)((float)v[2] * ss.y + (float)v[3] * cc.y);
        o[4] = (bf16_t)((float)v[4] * cc.z - (float)v[5] * ss.z);
        o[5] = (bf16_t)((float)v[4] * ss.z + (float)v[5] * cc.z);
        o[6] = (bf16_t)((float)v[6] * cc.w - (float)v[7] * ss.w);
        o[7] = (bf16_t)((float)v[6] * ss.w + (float)v[7] * cc.w);
        *reinterpret_cast<bf16x8*>(k + base) = o;
    }
}

// ---------------- flash attention ----------------
// Swapped QK^T: St = K*Q^T with row permutation sigma_p so each lane holds
// P[q=lane&15][kv = kv0 + g*8 + i]  (g = lane>>4, i = p*4+j) — exactly the
// B-fragment layout needed by PV (O^T = V^T * P^T). No cross-lane moves.
__global__ __launch_bounds__(256) void attn(
    const bf16_t* __restrict__ q, const bf16_t* __restrict__ k,
    const bf16_t* __restrict__ vt, bf16_t* __restrict__ y) {
    int lane = threadIdx.x & 63;
    int w = threadIdx.x >> 6;
    int rr = lane & 15, g = lane >> 4;
    int bh = blockIdx.y;
    int qbase = blockIdx.x * 64 + w * 16;
    int qrow = qbase + rr;
    const bf16_t* qh = q + (size_t)bh * T_ * HS_;
    const bf16_t* kh = k + (size_t)bh * T_ * HS_;
    const bf16_t* vh = vt + (size_t)bh * HS_ * T_;
    bf16x8 qf0 = *reinterpret_cast<const bf16x8*>(qh + (size_t)qrow * 64 + g * 8);
    bf16x8 qf1 = *reinterpret_cast<const bf16x8*>(qh + (size_t)qrow * 64 + 32 + g * 8);
    int s0 = ((rr >> 2) << 3) + (rr & 3);   // sigma_0 row; sigma_1 = +4
    float mrun = -1e30f, lsum = 0.f;
    f32x4 oacc[4] = {};
    int ntiles = (qbase >> 5) + 1;
    for (int tile = 0; tile < ntiles; ++tile) {
        int kv0 = tile << 5;
        f32x4 st0 = {0.f, 0.f, 0.f, 0.f}, st1 = {0.f, 0.f, 0.f, 0.f};
        const bf16_t* kr0 = kh + (size_t)(kv0 + s0) * 64;
        const bf16_t* kr1 = kr0 + 4 * 64;
        st0 = mfma16(*reinterpret_cast<const bf16x8*>(kr0 + g * 8), qf0, st0);
        st0 = mfma16(*reinterpret_cast<const bf16x8*>(kr0 + 32 + g * 8), qf1, st0);
        st1 = mfma16(*reinterpret_cast<const bf16x8*>(kr1 + g * 8), qf0, st1);
        st1 = mfma16(*reinterpret_cast<const bf16x8*>(kr1 + 32 + g * 8), qf1, st1);
        float sv[8];
        int kvl = kv0 + g * 8;
        #pragma unroll
        for (int j = 0; j < 4; ++j) { sv[j] = st0[j] * 0.125f; sv[4 + j] = st1[j] * 0.125f; }
        if (kv0 + 31 > qbase) {
            #pragma unroll
            for (int i = 0; i < 8; ++i)
                if (kvl + i > qrow) sv[i] = -1e30f;
        }
        float pmax = sv[0];
        #pragma unroll
        for (int i = 1; i < 8; ++i) pmax = fmaxf(pmax, sv[i]);
        pmax = fmaxf(pmax, __shfl_xor(pmax, 16));
        pmax = fmaxf(pmax, __shfl_xor(pmax, 32));
        float mnew = fmaxf(mrun, pmax);
        float fac = __expf(mrun - mnew);
        float psum = 0.f;
        bf16x8 pf;
        #pragma unroll
        for (int i = 0; i < 8; ++i) {
            float pe = __expf(sv[i] - mnew);
            psum += pe;
            pf[i] = (bf16_t)pe;
        }
        psum += __shfl_xor(psum, 16);
        psum += __shfl_xor(psum, 32);
        lsum = lsum * fac + psum;
        mrun = mnew;
        #pragma unroll
        for (int ch = 0; ch < 4; ++ch) {
            #pragma unroll
            for (int j = 0; j < 4; ++j) oacc[ch][j] *= fac;
        }
        #pragma unroll
        for (int ch = 0; ch < 4; ++ch) {
            bf16x8 vf = *reinterpret_cast<const bf16x8*>(vh + (size_t)(ch * 16 + rr) * 2048 + kv0 + g * 8);
            oacc[ch] = mfma16(vf, pf, oacc[ch]);
        }
    }
    float inv = 1.0f / lsum;
    int bI = bh >> 4, h = bh & 15;
    bf16_t* yrow = y + ((size_t)bI * 2048 + qrow) * 1024 + h * 64;
    #pragma unroll
    for (int ch = 0; ch < 4; ++ch) {
        union { bf16_t b[4]; short4 s4; } u;
        #pragma unroll
        for (int j = 0; j < 4; ++j) u.b[j] = (bf16_t)(oacc[ch][j] * inv);
        *reinterpret_cast<short4*>(yrow + ch * 16 + g * 4) = u.s4;
    }
}

// ---------------- projection GEMM ----------------
__global__ __launch_bounds__(256) void gemm_proj(
    const bf16_t* __restrict__ A, const bf16_t* __restrict__ Bt,
    const float* __restrict__ bp, float* __restrict__ out) {
    int lane = threadIdx.x & 63;
    int w = threadIdx.x >> 6;
    int rr = lane & 15, g = lane >> 4;
    int mbase = blockIdx.y * 128 + (w >> 1) * 64;
    int nbase = blockIdx.x * 128 + (w & 1) * 64;
    f32x4 acc[4][4] = {};
    const bf16_t* Ap = A + (size_t)(mbase + rr) * 1024 + g * 8;
    const bf16_t* Bp = Bt + (size_t)(nbase + rr) * 1024 + g * 8;
    for (int kk = 0; kk < 1024; kk += 32) {
        bf16x8 a[4], b[4];
        #pragma unroll
        for (int i = 0; i < 4; ++i) {
            a[i] = *reinterpret_cast<const bf16x8*>(Ap + i * 16 * 1024 + kk);
            b[i] = *reinterpret_cast<const bf16x8*>(Bp + i * 16 * 1024 + kk);
        }
        #pragma unroll
        for (int mi = 0; mi < 4; ++mi)
            #pragma unroll
            for (int ni = 0; ni < 4; ++ni)
                acc[mi][ni] = mfma16(a[mi], b[ni], acc[mi][ni]);
    }
    #pragma unroll
    for (int ni = 0; ni < 4; ++ni) {
        int n = nbase + ni * 16 + rr;
        float bias = bp[n];
        #pragma unroll
        for (int mi = 0; mi < 4; ++mi) {
            #pragma unroll
            for (int j = 0; j < 4; ++j) {
                int mrow = mbase + mi * 16 + g * 4 + j;
                out[(size_t)mrow * 1024 + n] = acc[mi][ni][j] + bias;
            }
        }
    }
}

// ---------------- launch ----------------
extern "C" void kernel_launch(void* const* d_in, const int* in_sizes, int n_in,
                              void* d_out, int out_size, void* d_ws, size_t ws_size,
                              hipStream_t stream) {
    const float* x  = (const float*)d_in[0];
    const float* Wq = (const float*)d_in[1];
    const float* bq = (const float*)d_in[2];
    const float* Wk = (const float*)d_in[3];
    const float* bk = (const float*)d_in[4];
    const float* Wv = (const float*)d_in[5];
    const float* bv = (const float*)d_in[6];
    const float* Wp = (const float*)d_in[7];
    const float* bp = (const float*)d_in[8];
    float* out = (float*)d_out;

    char* p = (char*)d_ws;
    auto alloc = [&](size_t n) { char* r = p; p += (n + 255) & ~(size_t)255; return r; };
    bf16_t* xb    = (bf16_t*)alloc((size_t)M_ * C_ * 2);
    bf16_t* wtqkv = (bf16_t*)alloc((size_t)3 * C_ * C_ * 2);
    bf16_t* wtp   = (bf16_t*)alloc((size_t)C_ * C_ * 2);
    bf16_t* qb    = (bf16_t*)alloc((size_t)BH_ * T_ * HS_ * 2);
    bf16_t* kb    = (bf16_t*)alloc((size_t)BH_ * T_ * HS_ * 2);
    bf16_t* vtb   = (bf16_t*)alloc((size_t)BH_ * HS_ * T_ * 2);
    bf16_t* yb    = (bf16_t*)alloc((size_t)M_ * C_ * 2);
    float*  cs    = (float*)alloc((size_t)T_ * 32 * 4);
    float*  sn    = (float*)alloc((size_t)T_ * 32 * 4);

    cvt_x<<<4096, 256, 0, stream>>>(x, xb);
    wtrans<<<dim3(32, 32), dim3(32, 8), 0, stream>>>(Wq, wtqkv);
    wtrans<<<dim3(32, 32), dim3(32, 8), 0, stream>>>(Wk, wtqkv + (size_t)C_ * C_);
    wtrans<<<dim3(32, 32), dim3(32, 8), 0, stream>>>(Wv, wtqkv + (size_t)2 * C_ * C_);
    wtrans<<<dim3(32, 32), dim3(32, 8), 0, stream>>>(Wp, wtp);
    rope_tab<<<256, 256, 0, stream>>>(cs, sn);

    gemm_qkv<<<dim3(24, 64), 256, 0, stream>>>(xb, wtqkv, bq, bk, bv, qb, kb, vtb);
    rope_qk<<<4096, 256, 0, stream>>>(qb, kb, cs, sn);
    attn<<<dim3(T_ / 64, BH_), 256, 0, stream>>>(qb, kb, vtb, yb);
    gemm_proj<<<dim3(8, 64), 256, 0, stream>>>(yb, wtp, bp, out);
}

// Round 3
// 669.196 us; speedup vs baseline: 1.2323x; 1.2323x over previous
//
#include <hip/hip_runtime.h>
#include <math.h>

#define B_  4
#define T_  2048
#define C_  1024
#define NH_ 16
#define HS_ 64
#define M_  (B_ * T_)          // 8192
#define BH_ (B_ * NH_)         // 64

typedef __bf16 bf16_t;
typedef __bf16 bf16x8 __attribute__((ext_vector_type(8)));
typedef float  f32x4  __attribute__((ext_vector_type(4)));

__device__ __forceinline__ f32x4 mfma16(bf16x8 a, bf16x8 b, f32x4 c) {
    return __builtin_amdgcn_mfma_f32_16x16x32_bf16(a, b, c, 0, 0, 0);
}

// ---------------- prep kernels ----------------

// x (fp32) -> bf16, 8 elements per thread
__global__ void cvt_x(const float* __restrict__ x, bf16_t* __restrict__ xb) {
    int i = blockIdx.x * blockDim.x + threadIdx.x;          // 1,048,576 threads
    const float4* src = reinterpret_cast<const float4*>(x);
    float4 u = src[2 * i], v = src[2 * i + 1];
    bf16x8 o;
    o[0] = (bf16_t)u.x; o[1] = (bf16_t)u.y; o[2] = (bf16_t)u.z; o[3] = (bf16_t)u.w;
    o[4] = (bf16_t)v.x; o[5] = (bf16_t)v.y; o[6] = (bf16_t)v.z; o[7] = (bf16_t)v.w;
    *reinterpret_cast<bf16x8*>(xb + (size_t)i * 8) = o;
}

// W[K=1024][N=1024] fp32 -> Wt[N][K] bf16 (tiled transpose via LDS)
__global__ void wtrans(const float* __restrict__ W, bf16_t* __restrict__ Wt) {
    __shared__ float tile[32][33];
    int bx = blockIdx.x, by = blockIdx.y;
    int tx = threadIdx.x, ty = threadIdx.y;
    #pragma unroll
    for (int j = 0; j < 4; ++j)
        tile[ty + j * 8][tx] = W[(size_t)(by * 32 + ty + j * 8) * 1024 + bx * 32 + tx];
    __syncthreads();
    #pragma unroll
    for (int j = 0; j < 4; ++j)
        Wt[(size_t)(bx * 32 + ty + j * 8) * 1024 + by * 32 + tx] = (bf16_t)tile[tx][ty + j * 8];
}

// cos/sin tables [T][32]
__global__ void rope_tab(float* __restrict__ cs, float* __restrict__ sn) {
    int idx = blockIdx.x * blockDim.x + threadIdx.x;        // 65536 threads
    int t = idx >> 5, j = idx & 31;
    float inv = 1.0f / powf(10000.0f, ((float)(2 * j)) / 64.0f);
    float ang = (float)t * inv;
    cs[idx] = cosf(ang);
    sn[idx] = sinf(ang);
}

// ---------------- QKV GEMM ----------------
__global__ __launch_bounds__(256) void gemm_qkv(
    const bf16_t* __restrict__ A, const bf16_t* __restrict__ Bt,
    const float* __restrict__ bq, const float* __restrict__ bk, const float* __restrict__ bv,
    bf16_t* __restrict__ outq, bf16_t* __restrict__ outk, bf16_t* __restrict__ outvt) {
    int lane = threadIdx.x & 63;
    int w = threadIdx.x >> 6;
    int rr = lane & 15, g = lane >> 4;
    int mbase = blockIdx.y * 128 + (w >> 1) * 64;
    int nbase = blockIdx.x * 128 + (w & 1) * 64;
    f32x4 acc[4][4] = {};
    const bf16_t* Ap = A + (size_t)(mbase + rr) * 1024 + g * 8;
    const bf16_t* Bp = Bt + (size_t)(nbase + rr) * 1024 + g * 8;
    for (int kk = 0; kk < 1024; kk += 32) {
        bf16x8 a[4], b[4];
        #pragma unroll
        for (int i = 0; i < 4; ++i) {
            a[i] = *reinterpret_cast<const bf16x8*>(Ap + i * 16 * 1024 + kk);
            b[i] = *reinterpret_cast<const bf16x8*>(Bp + i * 16 * 1024 + kk);
        }
        #pragma unroll
        for (int mi = 0; mi < 4; ++mi)
            #pragma unroll
            for (int ni = 0; ni < 4; ++ni)
                acc[mi][ni] = mfma16(a[mi], b[ni], acc[mi][ni]);
    }
    #pragma unroll
    for (int ni = 0; ni < 4; ++ni) {
        int n = nbase + ni * 16 + rr;
        int sel = n >> 10, nn = n & 1023, h = nn >> 6, d = nn & 63;
        float bias = (sel == 0) ? bq[nn] : (sel == 1) ? bk[nn] : bv[nn];
        #pragma unroll
        for (int mi = 0; mi < 4; ++mi) {
            #pragma unroll
            for (int j = 0; j < 4; ++j) {
                int mrow = mbase + mi * 16 + g * 4 + j;
                int bI = mrow >> 11, t = mrow & 2047;
                float val = acc[mi][ni][j] + bias;
                size_t bh = (size_t)(bI * 16 + h);
                if (sel == 0)      outq[(bh * 2048 + t) * 64 + d] = (bf16_t)val;
                else if (sel == 1) outk[(bh * 2048 + t) * 64 + d] = (bf16_t)val;
                else               outvt[(bh * 64 + d) * 2048 + t] = (bf16_t)val;
            }
        }
    }
}

// ---------------- RoPE on q,k (bf16 in-place) ----------------
__global__ void rope_qk(bf16_t* __restrict__ q, bf16_t* __restrict__ k,
                        const float* __restrict__ cs, const float* __restrict__ sn) {
    int idx = blockIdx.x * blockDim.x + threadIdx.x;        // BH*T*8 = 1,048,576
    int seg = idx & 7;
    int t = (idx >> 3) & 2047;
    int bh = idx >> 14;
    float4 cc = *reinterpret_cast<const float4*>(cs + (t << 5) + seg * 4);
    float4 ss = *reinterpret_cast<const float4*>(sn + (t << 5) + seg * 4);
    size_t base = (((size_t)bh << 11) + t) * 64 + seg * 8;
    {
        bf16x8 v = *reinterpret_cast<bf16x8*>(q + base);
        bf16x8 o;
        o[0] = (bf16_t)((float)v[0] * cc.x - (float)v[1] * ss.x);
        o[1] = (bf16_t)((float)v[0] * ss.x + (float)v[1] * cc.x);
        o[2] = (bf16_t)((float)v[2] * cc.y - (float)v[3] * ss.y);
        o[3] = (bf16_t)((float)v[2] * ss.y + (float)v[3] * cc.y);
        o[4] = (bf16_t)((float)v[4] * cc.z - (float)v[5] * ss.z);
        o[5] = (bf16_t)((float)v[4] * ss.z + (float)v[5] * cc.z);
        o[6] = (bf16_t)((float)v[6] * cc.w - (float)v[7] * ss.w);
        o[7] = (bf16_t)((float)v[6] * ss.w + (float)v[7] * cc.w);
        *reinterpret_cast<bf16x8*>(q + base) = o;
    }
    {
        bf16x8 v = *reinterpret_cast<bf16x8*>(k + base);
        bf16x8 o;
        o[0] = (bf16_t)((float)v[0] * cc.x - (float)v[1] * ss.x);
        o[1] = (bf16_t)((float)v[0] * ss.x + (float)v[1] * cc.x);
        o[2] = (bf16_t)((float)v[2] * cc.y - (float)v[3] * ss.y);
        o[3] = (bf16_t)((float)v[2] * ss.y + (float)v[3] * cc.y);
        o[4] = (bf16_t)((float)v[4] * cc.z - (float)v[5] * ss.z);
        o[5] = (bf16_t)((float)v[4] * ss.z + (float)v[5] * cc.z);
        o[6] = (bf16_t)((float)v[6] * cc.w - (float)v[7] * ss.w);
        o[7] = (bf16_t)((float)v[6] * ss.w + (float)v[7] * cc.w);
        *reinterpret_cast<bf16x8*>(k + base) = o;
    }
}

// ---------------- flash attention ----------------
// Swapped QK^T (St = K*Q^T with sigma row-permutation on K) so each lane holds
// P[q=lane&15][kv0 + g*8 + i] — exactly the PV B-fragment layout. No LDS.
// (1) register prefetch of next K/V tile (clamped, unconditional),
// (2) causal pairing — block handles q-tile x and 31-x for uniform work,
// (3) softmax in exp2 domain (scale folded with log2e).
__global__ __launch_bounds__(256) void attn(
    const bf16_t* __restrict__ q, const bf16_t* __restrict__ k,
    const bf16_t* __restrict__ vt, bf16_t* __restrict__ y) {
    int lane = threadIdx.x & 63;
    int w = threadIdx.x >> 6;
    int rr = lane & 15, g = lane >> 4;
    int bh = blockIdx.y;
    const bf16_t* qh = q + (size_t)bh * T_ * HS_;
    const bf16_t* kh = k + (size_t)bh * T_ * HS_;
    const bf16_t* vh = vt + (size_t)bh * HS_ * T_;
    int bI = bh >> 4, h = bh & 15;
    int s0 = ((rr >> 2) << 3) + (rr & 3);   // sigma_0 row; sigma_1 = +4
    const float SC = 0.125f * 1.44269504088896f;  // (1/sqrt(64)) * log2(e)

    #pragma unroll 1
    for (int pass = 0; pass < 2; ++pass) {
        int qt = pass ? (31 - (int)blockIdx.x) : (int)blockIdx.x;
        int qbase = qt * 64 + w * 16;
        int qrow = qbase + rr;
        bf16x8 qf0 = *reinterpret_cast<const bf16x8*>(qh + (size_t)qrow * 64 + g * 8);
        bf16x8 qf1 = *reinterpret_cast<const bf16x8*>(qh + (size_t)qrow * 64 + 32 + g * 8);
        float mrun = -1e30f, lsum = 0.f;
        f32x4 oacc[4] = {};
        int ntiles = (qbase >> 5) + 1;
        int lastkv = (ntiles - 1) << 5;
        // preload tile 0
        bf16x8 kc0, kc1, kc2, kc3, vc0, vc1, vc2, vc3;
        {
            const bf16_t* kr = kh + (size_t)s0 * 64;
            kc0 = *reinterpret_cast<const bf16x8*>(kr + g * 8);
            kc1 = *reinterpret_cast<const bf16x8*>(kr + 32 + g * 8);
            kc2 = *reinterpret_cast<const bf16x8*>(kr + 256 + g * 8);
            kc3 = *reinterpret_cast<const bf16x8*>(kr + 256 + 32 + g * 8);
            vc0 = *reinterpret_cast<const bf16x8*>(vh + (size_t)(rr) * 2048 + g * 8);
            vc1 = *reinterpret_cast<const bf16x8*>(vh + (size_t)(16 + rr) * 2048 + g * 8);
            vc2 = *reinterpret_cast<const bf16x8*>(vh + (size_t)(32 + rr) * 2048 + g * 8);
            vc3 = *reinterpret_cast<const bf16x8*>(vh + (size_t)(48 + rr) * 2048 + g * 8);
        }
        #pragma unroll 2
        for (int tile = 0; tile < ntiles; ++tile) {
            int kv0 = tile << 5;
            // prefetch next tile (clamped; redundant reload on last iter keeps schedule uniform)
            int nv0 = kv0 + 32; if (nv0 > lastkv) nv0 = lastkv;
            bf16x8 kn0, kn1, kn2, kn3, vn0, vn1, vn2, vn3;
            {
                const bf16_t* kr = kh + (size_t)(nv0 + s0) * 64;
                kn0 = *reinterpret_cast<const bf16x8*>(kr + g * 8);
                kn1 = *reinterpret_cast<const bf16x8*>(kr + 32 + g * 8);
                kn2 = *reinterpret_cast<const bf16x8*>(kr + 256 + g * 8);
                kn3 = *reinterpret_cast<const bf16x8*>(kr + 256 + 32 + g * 8);
                vn0 = *reinterpret_cast<const bf16x8*>(vh + (size_t)(rr) * 2048 + nv0 + g * 8);
                vn1 = *reinterpret_cast<const bf16x8*>(vh + (size_t)(16 + rr) * 2048 + nv0 + g * 8);
                vn2 = *reinterpret_cast<const bf16x8*>(vh + (size_t)(32 + rr) * 2048 + nv0 + g * 8);
                vn3 = *reinterpret_cast<const bf16x8*>(vh + (size_t)(48 + rr) * 2048 + nv0 + g * 8);
            }
            f32x4 st0 = {0.f, 0.f, 0.f, 0.f}, st1 = {0.f, 0.f, 0.f, 0.f};
            st0 = mfma16(kc0, qf0, st0);
            st0 = mfma16(kc1, qf1, st0);
            st1 = mfma16(kc2, qf0, st1);
            st1 = mfma16(kc3, qf1, st1);
            float sv[8];
            int kvl = kv0 + g * 8;
            #pragma unroll
            for (int j = 0; j < 4; ++j) { sv[j] = st0[j] * SC; sv[4 + j] = st1[j] * SC; }
            if (kv0 + 31 > qbase) {
                #pragma unroll
                for (int i = 0; i < 8; ++i)
                    if (kvl + i > qrow) sv[i] = -1e30f;
            }
            float pmax = sv[0];
            #pragma unroll
            for (int i = 1; i < 8; ++i) pmax = fmaxf(pmax, sv[i]);
            pmax = fmaxf(pmax, __shfl_xor(pmax, 16));
            pmax = fmaxf(pmax, __shfl_xor(pmax, 32));
            float mnew = fmaxf(mrun, pmax);
            float fac = __builtin_amdgcn_exp2f(mrun - mnew);
            float psum = 0.f;
            bf16x8 pf;
            #pragma unroll
            for (int i = 0; i < 8; ++i) {
                float pe = __builtin_amdgcn_exp2f(sv[i] - mnew);
                psum += pe;
                pf[i] = (bf16_t)pe;
            }
            psum += __shfl_xor(psum, 16);
            psum += __shfl_xor(psum, 32);
            lsum = lsum * fac + psum;
            mrun = mnew;
            #pragma unroll
            for (int ch = 0; ch < 4; ++ch) {
                #pragma unroll
                for (int j = 0; j < 4; ++j) oacc[ch][j] *= fac;
            }
            oacc[0] = mfma16(vc0, pf, oacc[0]);
            oacc[1] = mfma16(vc1, pf, oacc[1]);
            oacc[2] = mfma16(vc2, pf, oacc[2]);
            oacc[3] = mfma16(vc3, pf, oacc[3]);
            kc0 = kn0; kc1 = kn1; kc2 = kn2; kc3 = kn3;
            vc0 = vn0; vc1 = vn1; vc2 = vn2; vc3 = vn3;
        }
        float inv = 1.0f / lsum;
        bf16_t* yrow = y + ((size_t)bI * 2048 + qrow) * 1024 + h * 64;
        #pragma unroll
        for (int ch = 0; ch < 4; ++ch) {
            union { bf16_t b[4]; short4 s4; } u;
            #pragma unroll
            for (int j = 0; j < 4; ++j) u.b[j] = (bf16_t)(oacc[ch][j] * inv);
            *reinterpret_cast<short4*>(yrow + ch * 16 + g * 4) = u.s4;
        }
    }
}

// ---------------- projection GEMM ----------------
__global__ __launch_bounds__(256) void gemm_proj(
    const bf16_t* __restrict__ A, const bf16_t* __restrict__ Bt,
    const float* __restrict__ bp, float* __restrict__ out) {
    int lane = threadIdx.x & 63;
    int w = threadIdx.x >> 6;
    int rr = lane & 15, g = lane >> 4;
    int mbase = blockIdx.y * 128 + (w >> 1) * 64;
    int nbase = blockIdx.x * 128 + (w & 1) * 64;
    f32x4 acc[4][4] = {};
    const bf16_t* Ap = A + (size_t)(mbase + rr) * 1024 + g * 8;
    const bf16_t* Bp = Bt + (size_t)(nbase + rr) * 1024 + g * 8;
    for (int kk = 0; kk < 1024; kk += 32) {
        bf16x8 a[4], b[4];
        #pragma unroll
        for (int i = 0; i < 4; ++i) {
            a[i] = *reinterpret_cast<const bf16x8*>(Ap + i * 16 * 1024 + kk);
            b[i] = *reinterpret_cast<const bf16x8*>(Bp + i * 16 * 1024 + kk);
        }
        #pragma unroll
        for (int mi = 0; mi < 4; ++mi)
            #pragma unroll
            for (int ni = 0; ni < 4; ++ni)
                acc[mi][ni] = mfma16(a[mi], b[ni], acc[mi][ni]);
    }
    #pragma unroll
    for (int ni = 0; ni < 4; ++ni) {
        int n = nbase + ni * 16 + rr;
        float bias = bp[n];
        #pragma unroll
        for (int mi = 0; mi < 4; ++mi) {
            #pragma unroll
            for (int j = 0; j < 4; ++j) {
                int mrow = mbase + mi * 16 + g * 4 + j;
                out[(size_t)mrow * 1024 + n] = acc[mi][ni][j] + bias;
            }
        }
    }
}

// ---------------- launch ----------------
extern "C" void kernel_launch(void* const* d_in, const int* in_sizes, int n_in,
                              void* d_out, int out_size, void* d_ws, size_t ws_size,
                              hipStream_t stream) {
    const float* x  = (const float*)d_in[0];
    const float* Wq = (const float*)d_in[1];
    const float* bq = (const float*)d_in[2];
    const float* Wk = (const float*)d_in[3];
    const float* bk = (const float*)d_in[4];
    const float* Wv = (const float*)d_in[5];
    const float* bv = (const float*)d_in[6];
    const float* Wp = (const float*)d_in[7];
    const float* bp = (const float*)d_in[8];
    float* out = (float*)d_out;

    char* p = (char*)d_ws;
    auto alloc = [&](size_t n) { char* r = p; p += (n + 255) & ~(size_t)255; return r; };
    bf16_t* xb    = (bf16_t*)alloc((size_t)M_ * C_ * 2);
    bf16_t* wtqkv = (bf16_t*)alloc((size_t)3 * C_ * C_ * 2);
    bf16_t* wtp   = (bf16_t*)alloc((size_t)C_ * C_ * 2);
    bf16_t* qb    = (bf16_t*)alloc((size_t)BH_ * T_ * HS_ * 2);
    bf16_t* kb    = (bf16_t*)alloc((size_t)BH_ * T_ * HS_ * 2);
    bf16_t* vtb   = (bf16_t*)alloc((size_t)BH_ * HS_ * T_ * 2);
    bf16_t* yb    = (bf16_t*)alloc((size_t)M_ * C_ * 2);
    float*  cs    = (float*)alloc((size_t)T_ * 32 * 4);
    float*  sn    = (float*)alloc((size_t)T_ * 32 * 4);

    cvt_x<<<4096, 256, 0, stream>>>(x, xb);
    wtrans<<<dim3(32, 32), dim3(32, 8), 0, stream>>>(Wq, wtqkv);
    wtrans<<<dim3(32, 32), dim3(32, 8), 0, stream>>>(Wk, wtqkv + (size_t)C_ * C_);
    wtrans<<<dim3(32, 32), dim3(32, 8), 0, stream>>>(Wv, wtqkv + (size_t)2 * C_ * C_);
    wtrans<<<dim3(32, 32), dim3(32, 8), 0, stream>>>(Wp, wtp);
    rope_tab<<<256, 256, 0, stream>>>(cs, sn);

    gemm_qkv<<<dim3(24, 64), 256, 0, stream>>>(xb, wtqkv, bq, bk, bv, qb, kb, vtb);
    rope_qk<<<4096, 256, 0, stream>>>(qb, kb, cs, sn);
    attn<<<dim3(16, BH_), 256, 0, stream>>>(qb, kb, vtb, yb);
    gemm_proj<<<dim3(8, 64), 256, 0, stream>>>(yb, wtp, bp, out);
}

// Round 4
// 326.107 us; speedup vs baseline: 2.5287x; 2.0521x over previous
//
#include <hip/hip_runtime.h>
#include <math.h>

#define B_  4
#define T_  2048
#define C_  1024
#define NH_ 16
#define HS_ 64
#define M_  (B_ * T_)          // 8192
#define BH_ (B_ * NH_)         // 64

typedef __bf16 bf16_t;
typedef __bf16 bf16x8 __attribute__((ext_vector_type(8)));
typedef float  f32x4  __attribute__((ext_vector_type(4)));

__device__ __forceinline__ f32x4 mfma16(bf16x8 a, bf16x8 b, f32x4 c) {
    return __builtin_amdgcn_mfma_f32_16x16x32_bf16(a, b, c, 0, 0, 0);
}

// async global->LDS, 16B per lane. Dest semantics: wave-uniform base + lane*16
// (we always pass base+lane*16, so the per-lane pointer is consistent either way).
#define GLOAD16(gp, lp) __builtin_amdgcn_global_load_lds( \
    (const __attribute__((address_space(1))) void*)(gp),  \
    (__attribute__((address_space(3))) void*)(lp), 16, 0, 0)

// ---------------- prep kernels ----------------

__global__ void cvt_x(const float* __restrict__ x, bf16_t* __restrict__ xb) {
    int i = blockIdx.x * blockDim.x + threadIdx.x;
    const float4* src = reinterpret_cast<const float4*>(x);
    float4 u = src[2 * i], v = src[2 * i + 1];
    bf16x8 o;
    o[0] = (bf16_t)u.x; o[1] = (bf16_t)u.y; o[2] = (bf16_t)u.z; o[3] = (bf16_t)u.w;
    o[4] = (bf16_t)v.x; o[5] = (bf16_t)v.y; o[6] = (bf16_t)v.z; o[7] = (bf16_t)v.w;
    *reinterpret_cast<bf16x8*>(xb + (size_t)i * 8) = o;
}

__global__ void wtrans(const float* __restrict__ W, bf16_t* __restrict__ Wt) {
    __shared__ float tile[32][33];
    int bx = blockIdx.x, by = blockIdx.y;
    int tx = threadIdx.x, ty = threadIdx.y;
    #pragma unroll
    for (int j = 0; j < 4; ++j)
        tile[ty + j * 8][tx] = W[(size_t)(by * 32 + ty + j * 8) * 1024 + bx * 32 + tx];
    __syncthreads();
    #pragma unroll
    for (int j = 0; j < 4; ++j)
        Wt[(size_t)(bx * 32 + ty + j * 8) * 1024 + by * 32 + tx] = (bf16_t)tile[tx][ty + j * 8];
}

__global__ void rope_tab(float* __restrict__ cs, float* __restrict__ sn) {
    int idx = blockIdx.x * blockDim.x + threadIdx.x;
    int t = idx >> 5, j = idx & 31;
    float inv = 1.0f / powf(10000.0f, ((float)(2 * j)) / 64.0f);
    float ang = (float)t * inv;
    cs[idx] = cosf(ang);
    sn[idx] = sinf(ang);
}

// ---------------- QKV GEMM (m97-style LDS-staged) ----------------
// A [8192][1024], Bt [3072][1024]. 128x128 tile, BK=32, double-buffered LDS,
// global_load_lds width-16 staging. Epilogue scatters q,k:[BH][T][64], vt:[BH][64][T].
__global__ __launch_bounds__(256) void gemm_qkv(
    const bf16_t* __restrict__ A, const bf16_t* __restrict__ Bt,
    const float* __restrict__ bq, const float* __restrict__ bk, const float* __restrict__ bv,
    bf16_t* __restrict__ outq, bf16_t* __restrict__ outk, bf16_t* __restrict__ outvt) {
    __shared__ __align__(16) bf16_t Ab[2][128 * 32];
    __shared__ __align__(16) bf16_t Bb[2][128 * 32];
    int tid = threadIdx.x;
    int lane = tid & 63, w = tid >> 6;
    int rr = lane & 15, g = lane >> 4;
    int mbase = blockIdx.y * 128;
    int nbase = blockIdx.x * 128;
    int wm = (w >> 1) * 64, wn = (w & 1) * 64;
    f32x4 acc[4][4] = {};
    int r0 = tid >> 2, c0 = tid & 3;               // A/B tile: row=idx>>2, col16=idx&3
    const bf16_t* Asrc = A + (size_t)(mbase + r0) * 1024 + c0 * 8;
    const bf16_t* Bsrc = Bt + (size_t)(nbase + r0) * 1024 + c0 * 8;

    // prologue: stage k-tile 0 into buf 0
    GLOAD16(Asrc,             &Ab[0][tid * 8]);
    GLOAD16(Asrc + 64 * 1024, &Ab[0][(tid + 256) * 8]);
    GLOAD16(Bsrc,             &Bb[0][tid * 8]);
    GLOAD16(Bsrc + 64 * 1024, &Bb[0][(tid + 256) * 8]);
    __syncthreads();
    int cur = 0;
    for (int t = 0; t < 32; ++t) {
        if (t < 31) {
            int kk = (t + 1) * 32;
            GLOAD16(Asrc + kk,             &Ab[cur ^ 1][tid * 8]);
            GLOAD16(Asrc + 64 * 1024 + kk, &Ab[cur ^ 1][(tid + 256) * 8]);
            GLOAD16(Bsrc + kk,             &Bb[cur ^ 1][tid * 8]);
            GLOAD16(Bsrc + 64 * 1024 + kk, &Bb[cur ^ 1][(tid + 256) * 8]);
        }
        bf16x8 a[4], b[4];
        #pragma unroll
        for (int i = 0; i < 4; ++i) {
            a[i] = *(const bf16x8*)&Ab[cur][(wm + i * 16 + rr) * 32 + g * 8];
            b[i] = *(const bf16x8*)&Bb[cur][(wn + i * 16 + rr) * 32 + g * 8];
        }
        #pragma unroll
        for (int mi = 0; mi < 4; ++mi)
            #pragma unroll
            for (int ni = 0; ni < 4; ++ni)
                acc[mi][ni] = mfma16(a[mi], b[ni], acc[mi][ni]);
        __syncthreads();
        cur ^= 1;
    }
    #pragma unroll
    for (int ni = 0; ni < 4; ++ni) {
        int n = nbase + wn + ni * 16 + rr;
        int sel = n >> 10, nn = n & 1023, h = nn >> 6, d = nn & 63;
        float bias = (sel == 0) ? bq[nn] : (sel == 1) ? bk[nn] : bv[nn];
        #pragma unroll
        for (int mi = 0; mi < 4; ++mi) {
            #pragma unroll
            for (int j = 0; j < 4; ++j) {
                int mrow = mbase + wm + mi * 16 + g * 4 + j;
                int bI = mrow >> 11, t = mrow & 2047;
                float val = acc[mi][ni][j] + bias;
                size_t bh = (size_t)(bI * 16 + h);
                if (sel == 0)      outq[(bh * 2048 + t) * 64 + d] = (bf16_t)val;
                else if (sel == 1) outk[(bh * 2048 + t) * 64 + d] = (bf16_t)val;
                else               outvt[(bh * 64 + d) * 2048 + t] = (bf16_t)val;
            }
        }
    }
}

// ---------------- RoPE on q,k (bf16 in-place) ----------------
__global__ void rope_qk(bf16_t* __restrict__ q, bf16_t* __restrict__ k,
                        const float* __restrict__ cs, const float* __restrict__ sn) {
    int idx = blockIdx.x * blockDim.x + threadIdx.x;
    int seg = idx & 7;
    int t = (idx >> 3) & 2047;
    int bh = idx >> 14;
    float4 cc = *reinterpret_cast<const float4*>(cs + (t << 5) + seg * 4);
    float4 ss = *reinterpret_cast<const float4*>(sn + (t << 5) + seg * 4);
    size_t base = (((size_t)bh << 11) + t) * 64 + seg * 8;
    {
        bf16x8 v = *reinterpret_cast<bf16x8*>(q + base);
        bf16x8 o;
        o[0] = (bf16_t)((float)v[0] * cc.x - (float)v[1] * ss.x);
        o[1] = (bf16_t)((float)v[0] * ss.x + (float)v[1] * cc.x);
        o[2] = (bf16_t)((float)v[2] * cc.y - (float)v[3] * ss.y);
        o[3] = (bf16_t)((float)v[2] * ss.y + (float)v[3] * cc.y);
        o[4] = (bf16_t)((float)v[4] * cc.z - (float)v[5] * ss.z);
        o[5] = (bf16_t)((float)v[4] * ss.z + (float)v[5] * cc.z);
        o[6] = (bf16_t)((float)v[6] * cc.w - (float)v[7] * ss.w);
        o[7] = (bf16_t)((float)v[6] * ss.w + (float)v[7] * cc.w);
        *reinterpret_cast<bf16x8*>(q + base) = o;
    }
    {
        bf16x8 v = *reinterpret_cast<bf16x8*>(k + base);
        bf16x8 o;
        o[0] = (bf16_t)((float)v[0] * cc.x - (float)v[1] * ss.x);
        o[1] = (bf16_t)((float)v[0] * ss.x + (float)v[1] * cc.x);
        o[2] = (bf16_t)((float)v[2] * cc.y - (float)v[3] * ss.y);
        o[3] = (bf16_t)((float)v[2] * ss.y + (float)v[3] * cc.y);
        o[4] = (bf16_t)((float)v[4] * cc.z - (float)v[5] * ss.z);
        o[5] = (bf16_t)((float)v[4] * ss.z + (float)v[5] * cc.z);
        o[6] = (bf16_t)((float)v[6] * cc.w - (float)v[7] * ss.w);
        o[7] = (bf16_t)((float)v[6] * ss.w + (float)v[7] * cc.w);
        *reinterpret_cast<bf16x8*>(k + base) = o;
    }
}

// ---------------- flash attention (LDS-staged K/V, KVBLK=64) ----------------
// Swapped QK^T (St = K*Q^T, sigma row-perm on K) so lane holds P[q][kv] in the
// PV B-fragment layout. K/V tiles staged to LDS once per block (4 waves share),
// double-buffered, 2-phase pipeline. XOR-swizzled LDS (pre-swizzled global src).
__global__ __launch_bounds__(256) void attn(
    const bf16_t* __restrict__ q, const bf16_t* __restrict__ k,
    const bf16_t* __restrict__ vt, bf16_t* __restrict__ y) {
    __shared__ __align__(16) bf16_t Kb[2][64 * 64];
    __shared__ __align__(16) bf16_t Vb[2][64 * 64];
    int tid = threadIdx.x;
    int lane = tid & 63, w = tid >> 6;
    int rr = lane & 15, g = lane >> 4;
    // XCD-aware remap: blocks dispatched round-robin over 8 XCDs by raw id.
    int bid = blockIdx.x;                 // 1024 blocks
    int xcd = bid & 7, idx = bid >> 3;    // idx 0..127
    int bh = xcd * 8 + (idx >> 4);        // 8 heads per XCD -> KV set = 4MB L2
    int xp = idx & 15;                    // q-pair index 0..15
    const bf16_t* qh = q + (size_t)bh * T_ * HS_;
    const bf16_t* kh = k + (size_t)bh * T_ * HS_;
    const bf16_t* vh = vt + (size_t)bh * HS_ * T_;
    int bI = bh >> 4, h = bh & 15;
    int s0 = ((rr >> 2) << 3) + (rr & 3);
    const float SC = 0.125f * 1.44269504088896f;  // (1/sqrt(64)) * log2(e)

    // staging geometry: chunk idx2 in [0,512): row=idx2>>3, col16=idx2&7
    int i2a = tid, i2b = tid + 256;
    int rwa = i2a >> 3, rwb = i2b >> 3;
    int swKa = (rwa & 3) | (((rwa >> 3) & 1) << 2);
    int swKb = (rwb & 3) | (((rwb >> 3) & 1) << 2);
    int cKa = (i2a & 7) ^ swKa, cKb = (i2b & 7) ^ swKb;
    int cVa = (i2a & 7) ^ (rwa & 7), cVb = (i2b & 7) ^ (rwb & 7);

    #pragma unroll 1
    for (int pass = 0; pass < 2; ++pass) {
        int qt = pass ? (31 - xp) : xp;
        int qbase = qt * 64;
        int qrow = qbase + w * 16 + rr;
        bf16x8 qf0 = *reinterpret_cast<const bf16x8*>(qh + (size_t)qrow * 64 + g * 8);
        bf16x8 qf1 = *reinterpret_cast<const bf16x8*>(qh + (size_t)qrow * 64 + 32 + g * 8);
        float mrun = -1e30f, lsum = 0.f;
        f32x4 oacc[4] = {};
        int nt = qt + 1;
        // prologue: stage tile 0 -> buf 0
        GLOAD16(kh + (size_t)rwa * 64 + cKa * 8, &Kb[0][i2a * 8]);
        GLOAD16(kh + (size_t)rwb * 64 + cKb * 8, &Kb[0][i2b * 8]);
        GLOAD16(vh + (size_t)rwa * 2048 + cVa * 8, &Vb[0][i2a * 8]);
        GLOAD16(vh + (size_t)rwb * 2048 + cVb * 8, &Vb[0][i2b * 8]);
        __syncthreads();
        int cur = 0;
        #pragma unroll 1
        for (int t = 0; t < nt; ++t) {
            if (t + 1 < nt) {
                int kv1 = (t + 1) * 64;
                GLOAD16(kh + (size_t)(kv1 + rwa) * 64 + cKa * 8, &Kb[cur ^ 1][i2a * 8]);
                GLOAD16(kh + (size_t)(kv1 + rwb) * 64 + cKb * 8, &Kb[cur ^ 1][i2b * 8]);
                GLOAD16(vh + (size_t)rwa * 2048 + kv1 + cVa * 8, &Vb[cur ^ 1][i2a * 8]);
                GLOAD16(vh + (size_t)rwb * 2048 + kv1 + cVb * 8, &Vb[cur ^ 1][i2b * 8]);
            }
            int kv0 = t * 64;
            f32x4 st[4] = {};
            #pragma unroll
            for (int s = 0; s < 2; ++s) {
                #pragma unroll
                for (int p = 0; p < 2; ++p) {
                    int row = s * 32 + s0 + p * 4;
                    int sw = (row & 3) | (((row >> 3) & 1) << 2);
                    bf16x8 k0 = *(const bf16x8*)&Kb[cur][row * 64 + ((g ^ sw) * 8)];
                    bf16x8 k1 = *(const bf16x8*)&Kb[cur][row * 64 + (((4 + g) ^ sw) * 8)];
                    st[2 * s + p] = mfma16(k0, qf0, st[2 * s + p]);
                    st[2 * s + p] = mfma16(k1, qf1, st[2 * s + p]);
                }
            }
            float sv[16];
            #pragma unroll
            for (int s = 0; s < 2; ++s)
                #pragma unroll
                for (int p = 0; p < 2; ++p)
                    #pragma unroll
                    for (int j = 0; j < 4; ++j)
                        sv[s * 8 + p * 4 + j] = st[2 * s + p][j] * SC;
            if (t == nt - 1) {
                #pragma unroll
                for (int i = 0; i < 16; ++i) {
                    int kvi = kv0 + (i >> 3) * 32 + g * 8 + (i & 7);
                    if (kvi > qrow) sv[i] = -1e30f;
                }
            }
            float pmax = sv[0];
            #pragma unroll
            for (int i = 1; i < 16; ++i) pmax = fmaxf(pmax, sv[i]);
            pmax = fmaxf(pmax, __shfl_xor(pmax, 16));
            pmax = fmaxf(pmax, __shfl_xor(pmax, 32));
            float mnew = fmaxf(mrun, pmax);
            float fac = __builtin_amdgcn_exp2f(mrun - mnew);
            float psum = 0.f;
            bf16x8 pf0, pf1;
            #pragma unroll
            for (int i = 0; i < 8; ++i) {
                float pe = __builtin_amdgcn_exp2f(sv[i] - mnew);
                psum += pe;
                pf0[i] = (bf16_t)pe;
            }
            #pragma unroll
            for (int i = 0; i < 8; ++i) {
                float pe = __builtin_amdgcn_exp2f(sv[8 + i] - mnew);
                psum += pe;
                pf1[i] = (bf16_t)pe;
            }
            psum += __shfl_xor(psum, 16);
            psum += __shfl_xor(psum, 32);
            lsum = lsum * fac + psum;
            mrun = mnew;
            #pragma unroll
            for (int ch = 0; ch < 4; ++ch) {
                #pragma unroll
                for (int j = 0; j < 4; ++j) oacc[ch][j] *= fac;
            }
            #pragma unroll
            for (int ch = 0; ch < 4; ++ch) {
                int row = ch * 16 + rr;
                bf16x8 v0 = *(const bf16x8*)&Vb[cur][row * 64 + ((g ^ (row & 7)) * 8)];
                bf16x8 v1 = *(const bf16x8*)&Vb[cur][row * 64 + (((4 + g) ^ (row & 7)) * 8)];
                oacc[ch] = mfma16(v0, pf0, oacc[ch]);
                oacc[ch] = mfma16(v1, pf1, oacc[ch]);
            }
            __syncthreads();
            cur ^= 1;
        }
        float inv = 1.0f / lsum;
        bf16_t* yrow = y + ((size_t)bI * 2048 + qrow) * 1024 + h * 64;
        #pragma unroll
        for (int ch = 0; ch < 4; ++ch) {
            union { bf16_t b[4]; short4 s4; } u;
            #pragma unroll
            for (int j = 0; j < 4; ++j) u.b[j] = (bf16_t)(oacc[ch][j] * inv);
            *reinterpret_cast<short4*>(yrow + ch * 16 + g * 4) = u.s4;
        }
    }
}

// ---------------- projection GEMM (m97-style LDS-staged) ----------------
__global__ __launch_bounds__(256) void gemm_proj(
    const bf16_t* __restrict__ A, const bf16_t* __restrict__ Bt,
    const float* __restrict__ bp, float* __restrict__ out) {
    __shared__ __align__(16) bf16_t Ab[2][128 * 32];
    __shared__ __align__(16) bf16_t Bb[2][128 * 32];
    int tid = threadIdx.x;
    int lane = tid & 63, w = tid >> 6;
    int rr = lane & 15, g = lane >> 4;
    int mbase = blockIdx.y * 128;
    int nbase = blockIdx.x * 128;
    int wm = (w >> 1) * 64, wn = (w & 1) * 64;
    f32x4 acc[4][4] = {};
    int r0 = tid >> 2, c0 = tid & 3;
    const bf16_t* Asrc = A + (size_t)(mbase + r0) * 1024 + c0 * 8;
    const bf16_t* Bsrc = Bt + (size_t)(nbase + r0) * 1024 + c0 * 8;

    GLOAD16(Asrc,             &Ab[0][tid * 8]);
    GLOAD16(Asrc + 64 * 1024, &Ab[0][(tid + 256) * 8]);
    GLOAD16(Bsrc,             &Bb[0][tid * 8]);
    GLOAD16(Bsrc + 64 * 1024, &Bb[0][(tid + 256) * 8]);
    __syncthreads();
    int cur = 0;
    for (int t = 0; t < 32; ++t) {
        if (t < 31) {
            int kk = (t + 1) * 32;
            GLOAD16(Asrc + kk,             &Ab[cur ^ 1][tid * 8]);
            GLOAD16(Asrc + 64 * 1024 + kk, &Ab[cur ^ 1][(tid + 256) * 8]);
            GLOAD16(Bsrc + kk,             &Bb[cur ^ 1][tid * 8]);
            GLOAD16(Bsrc + 64 * 1024 + kk, &Bb[cur ^ 1][(tid + 256) * 8]);
        }
        bf16x8 a[4], b[4];
        #pragma unroll
        for (int i = 0; i < 4; ++i) {
            a[i] = *(const bf16x8*)&Ab[cur][(wm + i * 16 + rr) * 32 + g * 8];
            b[i] = *(const bf16x8*)&Bb[cur][(wn + i * 16 + rr) * 32 + g * 8];
        }
        #pragma unroll
        for (int mi = 0; mi < 4; ++mi)
            #pragma unroll
            for (int ni = 0; ni < 4; ++ni)
                acc[mi][ni] = mfma16(a[mi], b[ni], acc[mi][ni]);
        __syncthreads();
        cur ^= 1;
    }
    #pragma unroll
    for (int ni = 0; ni < 4; ++ni) {
        int n = nbase + wn + ni * 16 + rr;
        float bias = bp[n];
        #pragma unroll
        for (int mi = 0; mi < 4; ++mi) {
            #pragma unroll
            for (int j = 0; j < 4; ++j) {
                int mrow = mbase + wm + mi * 16 + g * 4 + j;
                out[(size_t)mrow * 1024 + n] = acc[mi][ni][j] + bias;
            }
        }
    }
}

// ---------------- launch ----------------
extern "C" void kernel_launch(void* const* d_in, const int* in_sizes, int n_in,
                              void* d_out, int out_size, void* d_ws, size_t ws_size,
                              hipStream_t stream) {
    const float* x  = (const float*)d_in[0];
    const float* Wq = (const float*)d_in[1];
    const float* bq = (const float*)d_in[2];
    const float* Wk = (const float*)d_in[3];
    const float* bk = (const float*)d_in[4];
    const float* Wv = (const float*)d_in[5];
    const float* bv = (const float*)d_in[6];
    const float* Wp = (const float*)d_in[7];
    const float* bp = (const float*)d_in[8];
    float* out = (float*)d_out;

    char* p = (char*)d_ws;
    auto alloc = [&](size_t n) { char* r = p; p += (n + 255) & ~(size_t)255; return r; };
    bf16_t* xb    = (bf16_t*)alloc((size_t)M_ * C_ * 2);
    bf16_t* wtqkv = (bf16_t*)alloc((size_t)3 * C_ * C_ * 2);
    bf16_t* wtp   = (bf16_t*)alloc((size_t)C_ * C_ * 2);
    bf16_t* qb    = (bf16_t*)alloc((size_t)BH_ * T_ * HS_ * 2);
    bf16_t* kb    = (bf16_t*)alloc((size_t)BH_ * T_ * HS_ * 2);
    bf16_t* vtb   = (bf16_t*)alloc((size_t)BH_ * HS_ * T_ * 2);
    bf16_t* yb    = (bf16_t*)alloc((size_t)M_ * C_ * 2);
    float*  cs    = (float*)alloc((size_t)T_ * 32 * 4);
    float*  sn    = (float*)alloc((size_t)T_ * 32 * 4);

    cvt_x<<<4096, 256, 0, stream>>>(x, xb);
    wtrans<<<dim3(32, 32), dim3(32, 8), 0, stream>>>(Wq, wtqkv);
    wtrans<<<dim3(32, 32), dim3(32, 8), 0, stream>>>(Wk, wtqkv + (size_t)C_ * C_);
    wtrans<<<dim3(32, 32), dim3(32, 8), 0, stream>>>(Wv, wtqkv + (size_t)2 * C_ * C_);
    wtrans<<<dim3(32, 32), dim3(32, 8), 0, stream>>>(Wp, wtp);
    rope_tab<<<256, 256, 0, stream>>>(cs, sn);

    gemm_qkv<<<dim3(24, 64), 256, 0, stream>>>(xb, wtqkv, bq, bk, bv, qb, kb, vtb);
    rope_qk<<<4096, 256, 0, stream>>>(qb, kb, cs, sn);
    attn<<<1024, 256, 0, stream>>>(qb, kb, vtb, yb);
    gemm_proj<<<dim3(8, 64), 256, 0, stream>>>(yb, wtp, bp, out);
}

// Round 5
// 318.689 us; speedup vs baseline: 2.5875x; 1.0233x over previous
//
#include <hip/hip_runtime.h>
#include <math.h>

#define B_  4
#define T_  2048
#define C_  1024
#define NH_ 16
#define HS_ 64
#define M_  (B_ * T_)          // 8192
#define BH_ (B_ * NH_)         // 64

typedef __bf16 bf16_t;
typedef __bf16 bf16x8 __attribute__((ext_vector_type(8)));
typedef float  f32x4  __attribute__((ext_vector_type(4)));

__device__ __forceinline__ f32x4 mfma16(bf16x8 a, bf16x8 b, f32x4 c) {
    return __builtin_amdgcn_mfma_f32_16x16x32_bf16(a, b, c, 0, 0, 0);
}

// async global->LDS, 16B per lane (dest = wave-uniform base + lane*16).
#define GLOAD16(gp, lp) __builtin_amdgcn_global_load_lds( \
    (const __attribute__((address_space(1))) void*)(gp),  \
    (__attribute__((address_space(3))) void*)(lp), 16, 0, 0)

// ---------------- prep kernels ----------------

__global__ void cvt_x(const float* __restrict__ x, bf16_t* __restrict__ xb) {
    int i = blockIdx.x * blockDim.x + threadIdx.x;
    const float4* src = reinterpret_cast<const float4*>(x);
    float4 u = src[2 * i], v = src[2 * i + 1];
    bf16x8 o;
    o[0] = (bf16_t)u.x; o[1] = (bf16_t)u.y; o[2] = (bf16_t)u.z; o[3] = (bf16_t)u.w;
    o[4] = (bf16_t)v.x; o[5] = (bf16_t)v.y; o[6] = (bf16_t)v.z; o[7] = (bf16_t)v.w;
    *reinterpret_cast<bf16x8*>(xb + (size_t)i * 8) = o;
}

__global__ void wtrans(const float* __restrict__ W, bf16_t* __restrict__ Wt) {
    __shared__ float tile[32][33];
    int bx = blockIdx.x, by = blockIdx.y;
    int tx = threadIdx.x, ty = threadIdx.y;
    #pragma unroll
    for (int j = 0; j < 4; ++j)
        tile[ty + j * 8][tx] = W[(size_t)(by * 32 + ty + j * 8) * 1024 + bx * 32 + tx];
    __syncthreads();
    #pragma unroll
    for (int j = 0; j < 4; ++j)
        Wt[(size_t)(bx * 32 + ty + j * 8) * 1024 + by * 32 + tx] = (bf16_t)tile[tx][ty + j * 8];
}

__global__ void rope_tab(float* __restrict__ cs, float* __restrict__ sn) {
    int idx = blockIdx.x * blockDim.x + threadIdx.x;
    int t = idx >> 5, j = idx & 31;
    float inv = 1.0f / powf(10000.0f, ((float)(2 * j)) / 64.0f);
    float ang = (float)t * inv;
    cs[idx] = cosf(ang);
    sn[idx] = sinf(ang);
}

// ---------------- QKV GEMM: 256Mx128N tile, BK=64, 8 waves ----------------
// LDS XOR-swizzle: LDS[row][ch] = G[row][ch ^ (row&7)] (16B chunks, 8/row).
// Staged via pre-swizzled global source + linear global_load_lds dest;
// ds_read applies the same XOR. Involution => reads return G[row][c].
__global__ __launch_bounds__(512) void gemm_qkv(
    const bf16_t* __restrict__ A, const bf16_t* __restrict__ Bt,
    const float* __restrict__ bq, const float* __restrict__ bk, const float* __restrict__ bv,
    bf16_t* __restrict__ outq, bf16_t* __restrict__ outk, bf16_t* __restrict__ outvt) {
    __shared__ __align__(16) bf16_t Ab[2][256 * 64];
    __shared__ __align__(16) bf16_t Bb[2][128 * 64];
    int tid = threadIdx.x;
    int lane = tid & 63, w = tid >> 6;           // 8 waves: 4M x 2N
    int rr = lane & 15, g = lane >> 4;
    // bijective XCD swizzle: nwg=768, cpx=96
    int lin = blockIdx.y * 24 + blockIdx.x;
    int swz = (lin & 7) * 96 + (lin >> 3);
    int bx = swz % 24, by = swz / 24;
    int mbase = by * 256, nbase = bx * 128;
    int wm = (w >> 1) * 64, wn = (w & 1) * 64;
    // staging: thread handles 16B chunk L = tid + j*512; row=L>>3, ch'=L&7.
    int rA = tid >> 3;                            // 0..63 (j adds 64)
    int cS = (tid & 7) ^ (rA & 7);                // source chunk (row&7 const over j)
    const bf16_t* Asrc = A + (size_t)(mbase + rA) * 1024 + cS * 8;
    const bf16_t* Bsrc = Bt + (size_t)(nbase + rA) * 1024 + cS * 8;
    // frag-read swizzled chunk offsets (elements): c = kk*4+g -> (c ^ (rr&7))*8
    int r7 = rr & 7;
    int ch0 = ((0 + g) ^ r7) * 8, ch1 = ((4 + g) ^ r7) * 8;
    f32x4 acc[4][4] = {};

    // prologue: stage k-tile 0 -> buf 0
    #pragma unroll
    for (int j = 0; j < 4; ++j) GLOAD16(Asrc + (size_t)j * 64 * 1024, &Ab[0][tid * 8 + j * 4096]);
    #pragma unroll
    for (int j = 0; j < 2; ++j) GLOAD16(Bsrc + (size_t)j * 64 * 1024, &Bb[0][tid * 8 + j * 4096]);
    __syncthreads();
    int cur = 0;
    for (int t = 0; t < 16; ++t) {
        if (t < 15) {
            int kk = (t + 1) * 64;
            #pragma unroll
            for (int j = 0; j < 4; ++j) GLOAD16(Asrc + kk + (size_t)j * 64 * 1024, &Ab[cur ^ 1][tid * 8 + j * 4096]);
            #pragma unroll
            for (int j = 0; j < 2; ++j) GLOAD16(Bsrc + kk + (size_t)j * 64 * 1024, &Bb[cur ^ 1][tid * 8 + j * 4096]);
        }
        #pragma unroll
        for (int kk = 0; kk < 2; ++kk) {
            int co = kk ? ch1 : ch0;
            bf16x8 a[4], b[4];
            #pragma unroll
            for (int i = 0; i < 4; ++i) {
                a[i] = *(const bf16x8*)&Ab[cur][(wm + i * 16 + rr) * 64 + co];
                b[i] = *(const bf16x8*)&Bb[cur][(wn + i * 16 + rr) * 64 + co];
            }
            #pragma unroll
            for (int mi = 0; mi < 4; ++mi)
                #pragma unroll
                for (int ni = 0; ni < 4; ++ni)
                    acc[mi][ni] = mfma16(a[mi], b[ni], acc[mi][ni]);
        }
        __syncthreads();
        cur ^= 1;
    }
    #pragma unroll
    for (int ni = 0; ni < 4; ++ni) {
        int n = nbase + wn + ni * 16 + rr;
        int sel = n >> 10, nn = n & 1023, h = nn >> 6, d = nn & 63;
        float bias = (sel == 0) ? bq[nn] : (sel == 1) ? bk[nn] : bv[nn];
        #pragma unroll
        for (int mi = 0; mi < 4; ++mi) {
            #pragma unroll
            for (int j = 0; j < 4; ++j) {
                int mrow = mbase + wm + mi * 16 + g * 4 + j;
                int bI = mrow >> 11, t = mrow & 2047;
                float val = acc[mi][ni][j] + bias;
                size_t bh = (size_t)(bI * 16 + h);
                if (sel == 0)      outq[(bh * 2048 + t) * 64 + d] = (bf16_t)val;
                else if (sel == 1) outk[(bh * 2048 + t) * 64 + d] = (bf16_t)val;
                else               outvt[(bh * 64 + d) * 2048 + t] = (bf16_t)val;
            }
        }
    }
}

// ---------------- RoPE on q,k (bf16 in-place) ----------------
__global__ void rope_qk(bf16_t* __restrict__ q, bf16_t* __restrict__ k,
                        const float* __restrict__ cs, const float* __restrict__ sn) {
    int idx = blockIdx.x * blockDim.x + threadIdx.x;
    int seg = idx & 7;
    int t = (idx >> 3) & 2047;
    int bh = idx >> 14;
    float4 cc = *reinterpret_cast<const float4*>(cs + (t << 5) + seg * 4);
    float4 ss = *reinterpret_cast<const float4*>(sn + (t << 5) + seg * 4);
    size_t base = (((size_t)bh << 11) + t) * 64 + seg * 8;
    {
        bf16x8 v = *reinterpret_cast<bf16x8*>(q + base);
        bf16x8 o;
        o[0] = (bf16_t)((float)v[0] * cc.x - (float)v[1] * ss.x);
        o[1] = (bf16_t)((float)v[0] * ss.x + (float)v[1] * cc.x);
        o[2] = (bf16_t)((float)v[2] * cc.y - (float)v[3] * ss.y);
        o[3] = (bf16_t)((float)v[2] * ss.y + (float)v[3] * cc.y);
        o[4] = (bf16_t)((float)v[4] * cc.z - (float)v[5] * ss.z);
        o[5] = (bf16_t)((float)v[4] * ss.z + (float)v[5] * cc.z);
        o[6] = (bf16_t)((float)v[6] * cc.w - (float)v[7] * ss.w);
        o[7] = (bf16_t)((float)v[6] * ss.w + (float)v[7] * cc.w);
        *reinterpret_cast<bf16x8*>(q + base) = o;
    }
    {
        bf16x8 v = *reinterpret_cast<bf16x8*>(k + base);
        bf16x8 o;
        o[0] = (bf16_t)((float)v[0] * cc.x - (float)v[1] * ss.x);
        o[1] = (bf16_t)((float)v[0] * ss.x + (float)v[1] * cc.x);
        o[2] = (bf16_t)((float)v[2] * cc.y - (float)v[3] * ss.y);
        o[3] = (bf16_t)((float)v[2] * ss.y + (float)v[3] * cc.y);
        o[4] = (bf16_t)((float)v[4] * cc.z - (float)v[5] * ss.z);
        o[5] = (bf16_t)((float)v[4] * ss.z + (float)v[5] * cc.z);
        o[6] = (bf16_t)((float)v[6] * cc.w - (float)v[7] * ss.w);
        o[7] = (bf16_t)((float)v[6] * ss.w + (float)v[7] * cc.w);
        *reinterpret_cast<bf16x8*>(k + base) = o;
    }
}

// ---------------- flash attention (unchanged from R4) ----------------
__global__ __launch_bounds__(256) void attn(
    const bf16_t* __restrict__ q, const bf16_t* __restrict__ k,
    const bf16_t* __restrict__ vt, bf16_t* __restrict__ y) {
    __shared__ __align__(16) bf16_t Kb[2][64 * 64];
    __shared__ __align__(16) bf16_t Vb[2][64 * 64];
    int tid = threadIdx.x;
    int lane = tid & 63, w = tid >> 6;
    int rr = lane & 15, g = lane >> 4;
    int bid = blockIdx.x;
    int xcd = bid & 7, idx = bid >> 3;
    int bh = xcd * 8 + (idx >> 4);
    int xp = idx & 15;
    const bf16_t* qh = q + (size_t)bh * T_ * HS_;
    const bf16_t* kh = k + (size_t)bh * T_ * HS_;
    const bf16_t* vh = vt + (size_t)bh * HS_ * T_;
    int bI = bh >> 4, h = bh & 15;
    int s0 = ((rr >> 2) << 3) + (rr & 3);
    const float SC = 0.125f * 1.44269504088896f;

    int i2a = tid, i2b = tid + 256;
    int rwa = i2a >> 3, rwb = i2b >> 3;
    int swKa = (rwa & 3) | (((rwa >> 3) & 1) << 2);
    int swKb = (rwb & 3) | (((rwb >> 3) & 1) << 2);
    int cKa = (i2a & 7) ^ swKa, cKb = (i2b & 7) ^ swKb;
    int cVa = (i2a & 7) ^ (rwa & 7), cVb = (i2b & 7) ^ (rwb & 7);

    #pragma unroll 1
    for (int pass = 0; pass < 2; ++pass) {
        int qt = pass ? (31 - xp) : xp;
        int qbase = qt * 64;
        int qrow = qbase + w * 16 + rr;
        bf16x8 qf0 = *reinterpret_cast<const bf16x8*>(qh + (size_t)qrow * 64 + g * 8);
        bf16x8 qf1 = *reinterpret_cast<const bf16x8*>(qh + (size_t)qrow * 64 + 32 + g * 8);
        float mrun = -1e30f, lsum = 0.f;
        f32x4 oacc[4] = {};
        int nt = qt + 1;
        GLOAD16(kh + (size_t)rwa * 64 + cKa * 8, &Kb[0][i2a * 8]);
        GLOAD16(kh + (size_t)rwb * 64 + cKb * 8, &Kb[0][i2b * 8]);
        GLOAD16(vh + (size_t)rwa * 2048 + cVa * 8, &Vb[0][i2a * 8]);
        GLOAD16(vh + (size_t)rwb * 2048 + cVb * 8, &Vb[0][i2b * 8]);
        __syncthreads();
        int cur = 0;
        #pragma unroll 1
        for (int t = 0; t < nt; ++t) {
            if (t + 1 < nt) {
                int kv1 = (t + 1) * 64;
                GLOAD16(kh + (size_t)(kv1 + rwa) * 64 + cKa * 8, &Kb[cur ^ 1][i2a * 8]);
                GLOAD16(kh + (size_t)(kv1 + rwb) * 64 + cKb * 8, &Kb[cur ^ 1][i2b * 8]);
                GLOAD16(vh + (size_t)rwa * 2048 + kv1 + cVa * 8, &Vb[cur ^ 1][i2a * 8]);
                GLOAD16(vh + (size_t)rwb * 2048 + kv1 + cVb * 8, &Vb[cur ^ 1][i2b * 8]);
            }
            int kv0 = t * 64;
            f32x4 st[4] = {};
            #pragma unroll
            for (int s = 0; s < 2; ++s) {
                #pragma unroll
                for (int p = 0; p < 2; ++p) {
                    int row = s * 32 + s0 + p * 4;
                    int sw = (row & 3) | (((row >> 3) & 1) << 2);
                    bf16x8 k0 = *(const bf16x8*)&Kb[cur][row * 64 + ((g ^ sw) * 8)];
                    bf16x8 k1 = *(const bf16x8*)&Kb[cur][row * 64 + (((4 + g) ^ sw) * 8)];
                    st[2 * s + p] = mfma16(k0, qf0, st[2 * s + p]);
                    st[2 * s + p] = mfma16(k1, qf1, st[2 * s + p]);
                }
            }
            float sv[16];
            #pragma unroll
            for (int s = 0; s < 2; ++s)
                #pragma unroll
                for (int p = 0; p < 2; ++p)
                    #pragma unroll
                    for (int j = 0; j < 4; ++j)
                        sv[s * 8 + p * 4 + j] = st[2 * s + p][j] * SC;
            if (t == nt - 1) {
                #pragma unroll
                for (int i = 0; i < 16; ++i) {
                    int kvi = kv0 + (i >> 3) * 32 + g * 8 + (i & 7);
                    if (kvi > qrow) sv[i] = -1e30f;
                }
            }
            float pmax = sv[0];
            #pragma unroll
            for (int i = 1; i < 16; ++i) pmax = fmaxf(pmax, sv[i]);
            pmax = fmaxf(pmax, __shfl_xor(pmax, 16));
            pmax = fmaxf(pmax, __shfl_xor(pmax, 32));
            float mnew = fmaxf(mrun, pmax);
            float fac = __builtin_amdgcn_exp2f(mrun - mnew);
            float psum = 0.f;
            bf16x8 pf0, pf1;
            #pragma unroll
            for (int i = 0; i < 8; ++i) {
                float pe = __builtin_amdgcn_exp2f(sv[i] - mnew);
                psum += pe;
                pf0[i] = (bf16_t)pe;
            }
            #pragma unroll
            for (int i = 0; i < 8; ++i) {
                float pe = __builtin_amdgcn_exp2f(sv[8 + i] - mnew);
                psum += pe;
                pf1[i] = (bf16_t)pe;
            }
            psum += __shfl_xor(psum, 16);
            psum += __shfl_xor(psum, 32);
            lsum = lsum * fac + psum;
            mrun = mnew;
            #pragma unroll
            for (int ch = 0; ch < 4; ++ch) {
                #pragma unroll
                for (int j = 0; j < 4; ++j) oacc[ch][j] *= fac;
            }
            #pragma unroll
            for (int ch = 0; ch < 4; ++ch) {
                int row = ch * 16 + rr;
                bf16x8 v0 = *(const bf16x8*)&Vb[cur][row * 64 + ((g ^ (row & 7)) * 8)];
                bf16x8 v1 = *(const bf16x8*)&Vb[cur][row * 64 + (((4 + g) ^ (row & 7)) * 8)];
                oacc[ch] = mfma16(v0, pf0, oacc[ch]);
                oacc[ch] = mfma16(v1, pf1, oacc[ch]);
            }
            __syncthreads();
            cur ^= 1;
        }
        float inv = 1.0f / lsum;
        bf16_t* yrow = y + ((size_t)bI * 2048 + qrow) * 1024 + h * 64;
        #pragma unroll
        for (int ch = 0; ch < 4; ++ch) {
            union { bf16_t b[4]; short4 s4; } u;
            #pragma unroll
            for (int j = 0; j < 4; ++j) u.b[j] = (bf16_t)(oacc[ch][j] * inv);
            *reinterpret_cast<short4*>(yrow + ch * 16 + g * 4) = u.s4;
        }
    }
}

// ---------------- projection GEMM: 256Mx128N, BK=64, 8 waves ----------------
__global__ __launch_bounds__(512) void gemm_proj(
    const bf16_t* __restrict__ A, const bf16_t* __restrict__ Bt,
    const float* __restrict__ bp, float* __restrict__ out) {
    __shared__ __align__(16) bf16_t Ab[2][256 * 64];
    __shared__ __align__(16) bf16_t Bb[2][128 * 64];
    int tid = threadIdx.x;
    int lane = tid & 63, w = tid >> 6;
    int rr = lane & 15, g = lane >> 4;
    // bijective XCD swizzle: nwg=256, cpx=32
    int lin = blockIdx.y * 8 + blockIdx.x;
    int swz = (lin & 7) * 32 + (lin >> 3);
    int bx = swz % 8, by = swz / 8;
    int mbase = by * 256, nbase = bx * 128;
    int wm = (w >> 1) * 64, wn = (w & 1) * 64;
    int rA = tid >> 3;
    int cS = (tid & 7) ^ (rA & 7);
    const bf16_t* Asrc = A + (size_t)(mbase + rA) * 1024 + cS * 8;
    const bf16_t* Bsrc = Bt + (size_t)(nbase + rA) * 1024 + cS * 8;
    int r7 = rr & 7;
    int ch0 = ((0 + g) ^ r7) * 8, ch1 = ((4 + g) ^ r7) * 8;
    f32x4 acc[4][4] = {};

    #pragma unroll
    for (int j = 0; j < 4; ++j) GLOAD16(Asrc + (size_t)j * 64 * 1024, &Ab[0][tid * 8 + j * 4096]);
    #pragma unroll
    for (int j = 0; j < 2; ++j) GLOAD16(Bsrc + (size_t)j * 64 * 1024, &Bb[0][tid * 8 + j * 4096]);
    __syncthreads();
    int cur = 0;
    for (int t = 0; t < 16; ++t) {
        if (t < 15) {
            int kk = (t + 1) * 64;
            #pragma unroll
            for (int j = 0; j < 4; ++j) GLOAD16(Asrc + kk + (size_t)j * 64 * 1024, &Ab[cur ^ 1][tid * 8 + j * 4096]);
            #pragma unroll
            for (int j = 0; j < 2; ++j) GLOAD16(Bsrc + kk + (size_t)j * 64 * 1024, &Bb[cur ^ 1][tid * 8 + j * 4096]);
        }
        #pragma unroll
        for (int kk = 0; kk < 2; ++kk) {
            int co = kk ? ch1 : ch0;
            bf16x8 a[4], b[4];
            #pragma unroll
            for (int i = 0; i < 4; ++i) {
                a[i] = *(const bf16x8*)&Ab[cur][(wm + i * 16 + rr) * 64 + co];
                b[i] = *(const bf16x8*)&Bb[cur][(wn + i * 16 + rr) * 64 + co];
            }
            #pragma unroll
            for (int mi = 0; mi < 4; ++mi)
                #pragma unroll
                for (int ni = 0; ni < 4; ++ni)
                    acc[mi][ni] = mfma16(a[mi], b[ni], acc[mi][ni]);
        }
        __syncthreads();
        cur ^= 1;
    }
    #pragma unroll
    for (int ni = 0; ni < 4; ++ni) {
        int n = nbase + wn + ni * 16 + rr;
        float bias = bp[n];
        #pragma unroll
        for (int mi = 0; mi < 4; ++mi) {
            #pragma unroll
            for (int j = 0; j < 4; ++j) {
                int mrow = mbase + wm + mi * 16 + g * 4 + j;
                out[(size_t)mrow * 1024 + n] = acc[mi][ni][j] + bias;
            }
        }
    }
}

// ---------------- launch ----------------
extern "C" void kernel_launch(void* const* d_in, const int* in_sizes, int n_in,
                              void* d_out, int out_size, void* d_ws, size_t ws_size,
                              hipStream_t stream) {
    const float* x  = (const float*)d_in[0];
    const float* Wq = (const float*)d_in[1];
    const float* bq = (const float*)d_in[2];
    const float* Wk = (const float*)d_in[3];
    const float* bk = (const float*)d_in[4];
    const float* Wv = (const float*)d_in[5];
    const float* bv = (const float*)d_in[6];
    const float* Wp = (const float*)d_in[7];
    const float* bp = (const float*)d_in[8];
    float* out = (float*)d_out;

    char* p = (char*)d_ws;
    auto alloc = [&](size_t n) { char* r = p; p += (n + 255) & ~(size_t)255; return r; };
    bf16_t* xb    = (bf16_t*)alloc((size_t)M_ * C_ * 2);
    bf16_t* wtqkv = (bf16_t*)alloc((size_t)3 * C_ * C_ * 2);
    bf16_t* wtp   = (bf16_t*)alloc((size_t)C_ * C_ * 2);
    bf16_t* qb    = (bf16_t*)alloc((size_t)BH_ * T_ * HS_ * 2);
    bf16_t* kb    = (bf16_t*)alloc((size_t)BH_ * T_ * HS_ * 2);
    bf16_t* vtb   = (bf16_t*)alloc((size_t)BH_ * HS_ * T_ * 2);
    bf16_t* yb    = (bf16_t*)alloc((size_t)M_ * C_ * 2);
    float*  cs    = (float*)alloc((size_t)T_ * 32 * 4);
    float*  sn    = (float*)alloc((size_t)T_ * 32 * 4);

    cvt_x<<<4096, 256, 0, stream>>>(x, xb);
    wtrans<<<dim3(32, 32), dim3(32, 8), 0, stream>>>(Wq, wtqkv);
    wtrans<<<dim3(32, 32), dim3(32, 8), 0, stream>>>(Wk, wtqkv + (size_t)C_ * C_);
    wtrans<<<dim3(32, 32), dim3(32, 8), 0, stream>>>(Wv, wtqkv + (size_t)2 * C_ * C_);
    wtrans<<<dim3(32, 32), dim3(32, 8), 0, stream>>>(Wp, wtp);
    rope_tab<<<256, 256, 0, stream>>>(cs, sn);

    gemm_qkv<<<dim3(24, 32), 512, 0, stream>>>(xb, wtqkv, bq, bk, bv, qb, kb, vtb);
    rope_qk<<<4096, 256, 0, stream>>>(qb, kb, cs, sn);
    attn<<<1024, 256, 0, stream>>>(qb, kb, vtb, yb);
    gemm_proj<<<dim3(8, 32), 512, 0, stream>>>(yb, wtp, bp, out);
}